// Round 4
// baseline (162.399 us; speedup 1.0000x reference)
//
#include <hip/hip_runtime.h>
#include <hip/hip_bf16.h>
#include <math.h>

// Problem constants
#define L_SEQ   1024
#define NB      8
#define H_DIM   300
#define KWIN    5
#define NREL    11          // 2K+1
#define PDIM    50
#define NC      11234       // band pair count for L=1024, K=5
#define BNC     (NB*NC)     // 89872
#define LN_EPS  1e-5f

#define KPAD    320         // K padded with zeros in [300,320)
#define WKSTR   320         // Wb k-stride (shorts) = KPAD (fq*8 reads stay in-row)
#define WNPAD   320         // Wb padded n rows

// Workspace layout (float offsets)
#define PREL_OFF  0                         // 11*300 fp32 (3300) -> pad 3328
#define WB_OFF    3328                      // 2*320*320 shorts = 102400 floats
#define AE_OFF    (3328 + 102400)           // 8192*300 shorts = 1228800 floats
// Ac follows Ae; total ~9.8 MiB

typedef __attribute__((ext_vector_type(8))) short s16x8;
typedef __attribute__((ext_vector_type(4))) short s16x4;
typedef __attribute__((ext_vector_type(4))) float f32x4;

// fp32 -> bf16 round-to-nearest-even
__device__ __forceinline__ short f2bf(float f) {
    unsigned u = __float_as_uint(f);
    u += 0x7fffu + ((u >> 16) & 1u);
    return (short)(u >> 16);
}
__device__ __forceinline__ float bf2f(short s) {
    return __uint_as_float(((unsigned)(unsigned short)s) << 16);
}

// band row start: first linear index n of row i (row-major over |j-i|<=5)
__device__ __forceinline__ int rowstart(int i) {
    if (i < 5)     return 6 * i + (i * (i - 1)) / 2;     // 0,6,13,21,30
    if (i <= 1018) return 40 + (i - 5) * 11;
    int d = i - 1019;                                     // widths 10,9,8,7,6
    return 11194 + d * 10 - (d * (d - 1)) / 2;            // 11194,11204,11213,11221,11228
}

// ---------------------------------------------------------------------------
// Kernel 1: prep.
//  blocks 0..12   : prel[r][h] = b1[h] + sum_d W1[h][600+d]*emb11[r][d]
//  blocks 13..812 : Wb[z][n][k] = bf16(W1[n][z*300+k]), zero-padded n>=300,k>=300
__global__ __launch_bounds__(256) void prep_kernel(
    const float* __restrict__ pos_W, const float* __restrict__ W1,
    const float* __restrict__ b1, float* __restrict__ prel,
    short* __restrict__ Wb)
{
    if (blockIdx.x < 13) {
        __shared__ float semb[NREL * PDIM];  // 550 floats
        for (int t = threadIdx.x; t < NREL * PDIM; t += 256) {
            int r = t / PDIM, d = t % PDIM;
            float acc = 0.f;
#pragma unroll
            for (int r2 = 0; r2 < NREL; ++r2) {
                float cnt = (float)(L_SEQ - abs(r2 - KWIN));
                int dr = r - r2;
                acc += cnt * expf(-(float)(dr * dr)) * pos_W[r2 * PDIM + d];
            }
            semb[t] = acc;
        }
        __syncthreads();
        int t = blockIdx.x * 256 + threadIdx.x;
        if (t < NREL * H_DIM) {
            int r = t / H_DIM, h = t % H_DIM;
            float acc = b1[h];
            const float* wrow = W1 + (size_t)h * 650 + 600;
            const float* em = semb + r * PDIM;
#pragma unroll 10
            for (int d = 0; d < PDIM; ++d) acc += wrow[d] * em[d];
            prel[t] = acc;
        }
    } else {
        int id = (blockIdx.x - 13) * 256 + threadIdx.x;
        if (id < 2 * WNPAD * WKSTR) {
            int z = id / (WNPAD * WKSTR);
            int rem = id % (WNPAD * WKSTR);
            int n = rem / WKSTR, k = rem % WKSTR;
            float v = (n < H_DIM && k < H_DIM) ? W1[(size_t)n * 650 + z * H_DIM + k] : 0.f;
            Wb[id] = f2bf(v);
        }
    }
}

// ---------------------------------------------------------------------------
// Kernel 2: merged dual GEMM, bf16 MFMA 16x16x32, full N per block.
//   Ae[m][n] = sum_k (h_e[m][k]+h_share[m][k]) * W1[n][k]
//   Ac[m][n] = sum_k (h_c[m][k]+h_share[m][k]) * W1[n][300+k]
// BM=32, BN=320 (all of N) -> A read exactly once from HBM.
// 512 threads = 8 waves; wave = (wz, wq): z-half and 80-wide n-slice.
// B fragments load directly from global Wb (L2-resident, 400 KB), only the
// 4 KB A tile goes through LDS. Grid 256 blocks = 1/CU.
__global__ __launch_bounds__(512) void gemm_fused(
    const float* __restrict__ h_e, const float* __restrict__ h_c,
    const float* __restrict__ h_share, const short* __restrict__ Wb,
    short* __restrict__ Ae, short* __restrict__ Ac)
{
    __shared__ __align__(16) short As[2 * 32 * 32];   // [z][row][k] 4 KB

    const int m0 = blockIdx.x * 32;
    const int tid = threadIdx.x;
    const int wave = tid >> 6, lane = tid & 63;
    const int wz = wave & 1;            // 0: Ae, 1: Ac
    const int wq = wave >> 1;           // n-slice (80 wide)
    const int fr = lane & 15, fq = lane >> 4;

    // A staging map: z = tid>>8, row = (tid>>3)&31, kc = (tid&7)*4
    const int sz   = tid >> 8;
    const int srow = (tid >> 3) & 31;
    const int skc  = (tid & 7) * 4;
    const float* X1 = sz ? h_c : h_e;
    const size_t abase = (size_t)(m0 + srow) * H_DIM;

    // B base for this wave's fragments (direct global)
    const short* wbase = Wb + ((size_t)wz * WNPAD + wq * 80 + fr) * WKSTR + fq * 8;

    f32x4 acc[2][5] = {};

    for (int k0 = 0; k0 < KPAD; k0 += 32) {
        // ---- stage A: bf16(h_x + h_share), 4 shorts per thread
        int k = k0 + skc;
        float x0 = 0.f, x1 = 0.f, x2 = 0.f, x3 = 0.f;
        if (k < H_DIM) {
            float4 u = *(const float4*)(X1 + abase + k);
            float4 v = *(const float4*)(h_share + abase + k);
            x0 = u.x + v.x; x1 = u.y + v.y; x2 = u.z + v.z; x3 = u.w + v.w;
        }
        s16x4 vv = { f2bf(x0), f2bf(x1), f2bf(x2), f2bf(x3) };
        *(s16x4*)&As[(sz * 32 + srow) * 32 + skc] = vv;

        // ---- B fragments straight from global (no LDS dependency)
        s16x8 bf[5];
#pragma unroll
        for (int nt = 0; nt < 5; ++nt)
            bf[nt] = *(const s16x8*)(wbase + (size_t)nt * 16 * WKSTR + k0);

        __syncthreads();
        s16x8 af0 = *(const s16x8*)&As[(wz * 32 + fr) * 32 + fq * 8];
        s16x8 af1 = *(const s16x8*)&As[(wz * 32 + 16 + fr) * 32 + fq * 8];
#pragma unroll
        for (int nt = 0; nt < 5; ++nt) {
            acc[0][nt] = __builtin_amdgcn_mfma_f32_16x16x32_bf16(af0, bf[nt], acc[0][nt], 0, 0, 0);
            acc[1][nt] = __builtin_amdgcn_mfma_f32_16x16x32_bf16(af1, bf[nt], acc[1][nt], 0, 0, 0);
        }
        __syncthreads();
    }

    // ---- store bf16. C/D layout: col = lane&15, row = fq*4 + reg
    short* C = wz ? Ac : Ae;
#pragma unroll
    for (int nt = 0; nt < 5; ++nt) {
        const int col = wq * 80 + nt * 16 + fr;
        if (col < H_DIM) {
#pragma unroll
            for (int mt = 0; mt < 2; ++mt) {
                const int rbase = m0 + mt * 16 + fq * 4;
#pragma unroll
                for (int r2 = 0; r2 < 4; ++r2)
                    C[(size_t)(rbase + r2) * H_DIM + col] = f2bf(acc[mt][nt][r2]);
            }
        }
    }
}

// ---------------------------------------------------------------------------
// Kernel 3: epilogue, tiled. Block = (b, i-tile of 32). Ae rows [i0,i0+32),
// Ac rows [i0-5,i0+37), prel all staged in LDS (58 KB); each row read once.
// 512 threads = 8 waves; wave processes pairs q = wave, wave+8, ...
__global__ __launch_bounds__(512) void epilogue_kernel(
    const short* __restrict__ Ae, const short* __restrict__ Ac,
    const float* __restrict__ prel,
    const float* __restrict__ ln_g, const float* __restrict__ ln_b,
    const float* __restrict__ W2, const float* __restrict__ b2,
    float* __restrict__ out, float* __restrict__ posout)
{
    __shared__ __align__(16) float prelL[NREL * 304];   // 13376 B
    __shared__ __align__(16) short EaL[32 * 304];       // 19456 B
    __shared__ __align__(16) short CaL[42 * 304];       // 25536 B

    const int tid = threadIdx.x;
    const int b   = blockIdx.x >> 5;
    const int i0  = (blockIdx.x & 31) * 32;
    const int jlo = i0 - KWIN;
    const int js  = jlo < 0 ? 0 : jlo;
    const int je  = (jlo + 42) < L_SEQ ? (jlo + 42) : L_SEQ;
    const int nrows = je - js;

    // prel -> LDS
    for (int q = tid; q < NREL * 75; q += 512) {
        int r = q / 75, kc = (q % 75) * 4;
        *(float4*)&prelL[r * 304 + kc] = *(const float4*)(prel + q * 4);
    }
    // Ae rows -> LDS (contiguous global span, 8B chunks)
    {
        const short* g = Ae + ((size_t)b * L_SEQ + i0) * H_DIM;
        for (int q = tid; q < 32 * 75; q += 512) {
            int r = q / 75, kc = (q % 75) * 4;
            *(s16x4*)&EaL[r * 304 + kc] = *(const s16x4*)(g + q * 4);
        }
    }
    // Ac rows [js, je) -> LDS slots js-jlo ..
    {
        const short* g = Ac + ((size_t)b * L_SEQ + js) * H_DIM;
        const int sbase = (js - jlo) * 304;
        for (int q = tid; q < nrows * 75; q += 512) {
            int r = q / 75, kc = (q % 75) * 4;
            *(s16x4*)&CaL[sbase + r * 304 + kc] = *(const s16x4*)(g + q * 4);
        }
    }
    __syncthreads();

    const int wave = tid >> 6, lane = tid & 63;
    const float b2v = b2[0];

    const int c0 = lane * 4;          // 0..252
    const int c1 = 256 + lane * 4;    // tail: lanes 0..10
    const bool tail = lane < 11;
    const float4 g0 = *(const float4*)(ln_g + c0);
    const float4 bb0 = *(const float4*)(ln_b + c0);
    const float4 w0 = *(const float4*)(W2 + c0);
    float4 g1 = {0,0,0,0}, bb1 = {0,0,0,0}, w1 = {0,0,0,0};
    if (tail) {
        g1 = *(const float4*)(ln_g + c1);
        bb1 = *(const float4*)(ln_b + c1);
        w1 = *(const float4*)(W2 + c1);
    }

    for (int q = wave; q < 32 * NREL; q += 8) {
        const int di = q / NREL, r = q % NREL;
        const int ii = i0 + di;
        const int j  = ii - KWIN + r;
        if (j < 0 || j >= L_SEQ) continue;   // wave-uniform

        const short* ea = EaL + di * 304;
        const short* ca = CaL + (j - jlo) * 304;
        const float* pr = prelL + r * 304;

        s16x4 a0 = *(const s16x4*)(ea + c0);
        s16x4 d0 = *(const s16x4*)(ca + c0);
        float4 p0 = *(const float4*)(pr + c0);
        float4 h0 = make_float4(bf2f(a0.x) + bf2f(d0.x) + p0.x,
                                bf2f(a0.y) + bf2f(d0.y) + p0.y,
                                bf2f(a0.z) + bf2f(d0.z) + p0.z,
                                bf2f(a0.w) + bf2f(d0.w) + p0.w);
        float4 h1 = make_float4(0.f, 0.f, 0.f, 0.f);
        if (tail) {
            s16x4 a1 = *(const s16x4*)(ea + c1);
            s16x4 d1 = *(const s16x4*)(ca + c1);
            float4 p1 = *(const float4*)(pr + c1);
            h1 = make_float4(bf2f(a1.x) + bf2f(d1.x) + p1.x,
                             bf2f(a1.y) + bf2f(d1.y) + p1.y,
                             bf2f(a1.z) + bf2f(d1.z) + p1.z,
                             bf2f(a1.w) + bf2f(d1.w) + p1.w);
        }

        float s  = h0.x + h0.y + h0.z + h0.w + h1.x + h1.y + h1.z + h1.w;
        float ss = h0.x*h0.x + h0.y*h0.y + h0.z*h0.z + h0.w*h0.w
                 + h1.x*h1.x + h1.y*h1.y + h1.z*h1.z + h1.w*h1.w;
#pragma unroll
        for (int off = 32; off > 0; off >>= 1) {
            s  += __shfl_xor(s, off);
            ss += __shfl_xor(ss, off);
        }
        const float mu   = s * (1.f / H_DIM);
        const float var  = ss * (1.f / H_DIM) - mu * mu;
        const float rsig = rsqrtf(var + LN_EPS);

        float e0 = (h0.x - mu) * rsig * g0.x + bb0.x;
        float e1 = (h0.y - mu) * rsig * g0.y + bb0.y;
        float e2 = (h0.z - mu) * rsig * g0.z + bb0.z;
        float e3 = (h0.w - mu) * rsig * g0.w + bb0.w;
        e0 = e0 > 0.f ? e0 : __expf(e0) - 1.f;
        e1 = e1 > 0.f ? e1 : __expf(e1) - 1.f;
        e2 = e2 > 0.f ? e2 : __expf(e2) - 1.f;
        e3 = e3 > 0.f ? e3 : __expf(e3) - 1.f;
        float acc = e0 * w0.x + e1 * w0.y + e2 * w0.z + e3 * w0.w;
        if (tail) {
            float f0 = (h1.x - mu) * rsig * g1.x + bb1.x;
            float f1 = (h1.y - mu) * rsig * g1.y + bb1.y;
            float f2 = (h1.z - mu) * rsig * g1.z + bb1.z;
            float f3 = (h1.w - mu) * rsig * g1.w + bb1.w;
            f0 = f0 > 0.f ? f0 : __expf(f0) - 1.f;
            f1 = f1 > 0.f ? f1 : __expf(f1) - 1.f;
            f2 = f2 > 0.f ? f2 : __expf(f2) - 1.f;
            f3 = f3 > 0.f ? f3 : __expf(f3) - 1.f;
            acc += f0 * w1.x + f1 * w1.y + f2 * w1.z + f3 * w1.w;
        }
#pragma unroll
        for (int off = 32; off > 0; off >>= 1) acc += __shfl_xor(acc, off);

        if (lane == 0) {
            const int jb = ii - KWIN < 0 ? 0 : ii - KWIN;
            const int n = rowstart(ii) + (j - jb);
            out[(size_t)b * NC + n] = acc + b2v;
            if (b == 0) {
                posout[2 * (size_t)n]     = (float)(ii + 1);
                posout[2 * (size_t)n + 1] = (float)(j + 1);
            }
        }
    }
}

// ---------------------------------------------------------------------------
extern "C" void kernel_launch(void* const* d_in, const int* in_sizes, int n_in,
                              void* d_out, int out_size, void* d_ws, size_t ws_size,
                              hipStream_t stream) {
    const float* h_e     = (const float*)d_in[0];
    const float* h_c     = (const float*)d_in[1];
    const float* h_share = (const float*)d_in[2];
    // d_in[3] = mask (unused)
    const float* pos_W   = (const float*)d_in[4];
    const float* W1      = (const float*)d_in[5];
    const float* b1      = (const float*)d_in[6];
    const float* ln_g    = (const float*)d_in[7];
    const float* ln_b    = (const float*)d_in[8];
    const float* W2      = (const float*)d_in[9];
    const float* b2      = (const float*)d_in[10];

    float* ws   = (float*)d_ws;
    float* prel = ws + PREL_OFF;
    short* Wb   = (short*)(ws + WB_OFF);
    short* Ae   = (short*)(ws + AE_OFF);
    short* Ac   = Ae + (size_t)NB * L_SEQ * H_DIM;

    float* out    = (float*)d_out;
    float* posout = out + BNC;

    prep_kernel<<<13 + (2 * WNPAD * WKSTR) / 256, 256, 0, stream>>>(
        pos_W, W1, b1, prel, Wb);

    gemm_fused<<<NB * L_SEQ / 32, 512, 0, stream>>>(
        h_e, h_c, h_share, Wb, Ae, Ac);

    epilogue_kernel<<<NB * (L_SEQ / 32), 512, 0, stream>>>(
        Ae, Ac, prel, ln_g, ln_b, W2, b2, out, posout);
}

// Round 5
// 136.184 us; speedup vs baseline: 1.1925x; 1.1925x over previous
//
#include <hip/hip_runtime.h>
#include <hip/hip_bf16.h>
#include <math.h>

// Problem constants
#define L_SEQ   1024
#define NB      8
#define H_DIM   300
#define KWIN    5
#define NREL    11          // 2K+1
#define PDIM    50
#define NC      11234       // band pair count for L=1024, K=5
#define BNC     (NB*NC)     // 89872
#define LN_EPS  1e-5f

#define KPAD    320         // K padded with zeros in [300,320)
#define WKSTR   320         // Wb k-stride (shorts)
#define WNPAD   320         // Wb padded n rows

#define ITILE   16          // i rows per block
#define XROWS   48          // 16 Xe rows + 32 Xc rows (halo i0-5 .. i0+26)
#define XSTR    328         // X row stride in shorts (656 B; 164 words = 4 mod 32)

// Workspace layout (float offsets)
#define PREL_OFF  0                         // 11*300 fp32 -> pad 3328
#define WB_OFF    3328                      // 2*320*320 shorts = 102400 floats

typedef __attribute__((ext_vector_type(8))) short s16x8;
typedef __attribute__((ext_vector_type(4))) short s16x4;
typedef __attribute__((ext_vector_type(4))) float f32x4;

// fp32 -> bf16 round-to-nearest-even
__device__ __forceinline__ short f2bf(float f) {
    unsigned u = __float_as_uint(f);
    u += 0x7fffu + ((u >> 16) & 1u);
    return (short)(u >> 16);
}
__device__ __forceinline__ float bf2f(short s) {
    return __uint_as_float(((unsigned)(unsigned short)s) << 16);
}

// band row start: first linear index n of row i (row-major over |j-i|<=5)
__device__ __forceinline__ int rowstart(int i) {
    if (i < 5)     return 6 * i + (i * (i - 1)) / 2;     // 0,6,13,21,30
    if (i <= 1018) return 40 + (i - 5) * 11;
    int d = i - 1019;                                     // widths 10,9,8,7,6
    return 11194 + d * 10 - (d * (d - 1)) / 2;
}

// ---------------------------------------------------------------------------
// Kernel 1: prep.
//  blocks 0..12   : prel[r][h] = b1[h] + sum_d W1[h][600+d]*emb11[r][d]
//  blocks 13..812 : Wb[z][n][k] = bf16(W1[n][z*300+k]), zero-padded n>=300,k>=300
__global__ __launch_bounds__(256) void prep_kernel(
    const float* __restrict__ pos_W, const float* __restrict__ W1,
    const float* __restrict__ b1, float* __restrict__ prel,
    short* __restrict__ Wb)
{
    if (blockIdx.x < 13) {
        __shared__ float semb[NREL * PDIM];
        for (int t = threadIdx.x; t < NREL * PDIM; t += 256) {
            int r = t / PDIM, d = t % PDIM;
            float acc = 0.f;
#pragma unroll
            for (int r2 = 0; r2 < NREL; ++r2) {
                float cnt = (float)(L_SEQ - abs(r2 - KWIN));
                int dr = r - r2;
                acc += cnt * expf(-(float)(dr * dr)) * pos_W[r2 * PDIM + d];
            }
            semb[t] = acc;
        }
        __syncthreads();
        int t = blockIdx.x * 256 + threadIdx.x;
        if (t < NREL * H_DIM) {
            int r = t / H_DIM, h = t % H_DIM;
            float acc = b1[h];
            const float* wrow = W1 + (size_t)h * 650 + 600;
            const float* em = semb + r * PDIM;
#pragma unroll 10
            for (int d = 0; d < PDIM; ++d) acc += wrow[d] * em[d];
            prel[t] = acc;
        }
    } else {
        int id = (blockIdx.x - 13) * 256 + threadIdx.x;
        if (id < 2 * WNPAD * WKSTR) {
            int z = id / (WNPAD * WKSTR);
            int rem = id % (WNPAD * WKSTR);
            int n = rem / WKSTR, k = rem % WKSTR;
            float v = (n < H_DIM && k < H_DIM) ? W1[(size_t)n * 650 + z * H_DIM + k] : 0.f;
            Wb[id] = f2bf(v);
        }
    }
}

// ---------------------------------------------------------------------------
// Kernel 2: fused GEMM + epilogue. Block = (b, i-tile of 16). 512 threads.
// Phase 1: stage X (full K) -> MFMA vs L2-resident Wb -> results back to X (bf16)
// Phase 2: per-pair LN+ELU+dot, 16 lanes/pair, 4-step butterflies.
__global__ __launch_bounds__(512) void fused_kernel(
    const float* __restrict__ h_e, const float* __restrict__ h_c,
    const float* __restrict__ h_share, const short* __restrict__ Wb,
    const float* __restrict__ prel,
    const float* __restrict__ ln_g, const float* __restrict__ ln_b,
    const float* __restrict__ W2, const float* __restrict__ b2,
    float* __restrict__ out, float* __restrict__ posout)
{
    __shared__ __align__(16) short X[XROWS * XSTR];   // 31488 B

    const int tid = threadIdx.x;
    const int b   = blockIdx.x >> 6;          // 64 i-tiles
    const int i0  = (blockIdx.x & 63) * ITILE;

    // ---- zero pad cols [304,328)
    for (int t = tid; t < XROWS * 3; t += 512) {
        int row = t / 3, c = 304 + (t % 3) * 8;
        *(s16x8*)&X[row * XSTR + c] = (s16x8){0,0,0,0,0,0,0,0};
    }
    // ---- stage X: rows 0..15 = bf16(he+hs)[i0+row]; rows 16..47 = bf16(hc+hs)[i0-5+row-16]
    for (int t = tid; t < XROWS * 76; t += 512) {
        int row = t / 76, kc = (t % 76) * 4;  // kc=300 chunk -> zeros into [300,304)
        float4 a = make_float4(0.f,0.f,0.f,0.f), s4 = a;
        int gr; const float* base;
        if (row < 16) { gr = i0 + row; base = h_e; }
        else          { gr = i0 - 5 + (row - 16); base = h_c; }
        bool valid = (kc < H_DIM) && (gr >= 0) && (gr < L_SEQ);
        if (valid) {
            size_t off = ((size_t)b * L_SEQ + gr) * H_DIM + kc;
            a  = *(const float4*)(base + off);
            s4 = *(const float4*)(h_share + off);
        }
        s16x4 v = { f2bf(a.x + s4.x), f2bf(a.y + s4.y),
                    f2bf(a.z + s4.z), f2bf(a.w + s4.w) };
        *(s16x4*)&X[row * XSTR + kc] = v;
    }
    __syncthreads();

    // ---- GEMM phase. 8 waves: wz = wave>>2 (0:Ae rows 0..15, 1:Ac rows 16..47),
    // n-slice = (wave&3)*80 (5 frags of 16).
    const int wave = tid >> 6, lane = tid & 63;
    const int fr = lane & 15, fq = lane >> 4;
    const int wz  = wave >> 2;
    const int nsl = (wave & 3) * 80;
    const short* wbase = Wb + ((size_t)wz * WNPAD + nsl + fr) * WKSTR + fq * 8;

    f32x4 acc0[5] = {};
    f32x4 acc1[5] = {};

    for (int k0 = 0; k0 < KPAD; k0 += 32) {
        s16x8 bf[5];
#pragma unroll
        for (int nt = 0; nt < 5; ++nt)
            bf[nt] = *(const s16x8*)(wbase + (size_t)nt * 16 * WKSTR + k0);
        const int mrow0 = wz ? (16 + fr) : fr;
        s16x8 af0 = *(const s16x8*)&X[mrow0 * XSTR + k0 + fq * 8];
#pragma unroll
        for (int nt = 0; nt < 5; ++nt)
            acc0[nt] = __builtin_amdgcn_mfma_f32_16x16x32_bf16(af0, bf[nt], acc0[nt], 0, 0, 0);
        if (wz) {
            s16x8 af1 = *(const s16x8*)&X[(32 + fr) * XSTR + k0 + fq * 8];
#pragma unroll
            for (int nt = 0; nt < 5; ++nt)
                acc1[nt] = __builtin_amdgcn_mfma_f32_16x16x32_bf16(af1, bf[nt], acc1[nt], 0, 0, 0);
        }
    }
    __syncthreads();   // all waves done reading X inputs

    // ---- write results into X (bf16). C/D layout: col=lane&15, row=fq*4+reg.
#pragma unroll
    for (int nt = 0; nt < 5; ++nt) {
        const int col = nsl + nt * 16 + fr;
        if (col < H_DIM) {
            const int rb0 = (wz ? 16 : 0) + fq * 4;
#pragma unroll
            for (int r2 = 0; r2 < 4; ++r2)
                X[(rb0 + r2) * XSTR + col] = f2bf(acc0[nt][r2]);
            if (wz) {
                const int rb1 = 32 + fq * 4;
#pragma unroll
                for (int r2 = 0; r2 < 4; ++r2)
                    X[(rb1 + r2) * XSTR + col] = f2bf(acc1[nt][r2]);
            }
        }
    }
    __syncthreads();

    // ---- Epilogue phase: 16 lanes per pair, 4 pairs/wave, 6 rounds.
    const int quad = lane >> 4, fl = lane & 15;
    const float b2v = b2[0];
    const float inv = 1.f / (float)H_DIM;

    for (int round = 0; round < 6; ++round) {
        int q = round * 32 + wave * 4 + quad;       // 0..191; 176 real pairs
        int qc = q < 175 ? q : 175;
        int di = qc / NREL, r = qc % NREL;
        int ii = i0 + di, j = ii - KWIN + r;
        bool active = (q < ITILE * NREL) && (j >= 0) && (j < L_SEQ);

        const int ea_off = di * XSTR;
        const int ca_off = (16 + di + r) * XSTR;
        const float* prow = prel + r * H_DIM;

        float h[20];
        float s = 0.f, ss = 0.f;
#pragma unroll
        for (int w5 = 0; w5 < 5; ++w5) {
            int c = w5 * 64 + fl * 4;
            float4 hv = make_float4(0.f,0.f,0.f,0.f);
            if (c < H_DIM) {
                s16x4 ea = *(const s16x4*)&X[ea_off + c];
                s16x4 ca = *(const s16x4*)&X[ca_off + c];
                float4 p = *(const float4*)(prow + c);
                hv.x = bf2f(ea.x) + bf2f(ca.x) + p.x;
                hv.y = bf2f(ea.y) + bf2f(ca.y) + p.y;
                hv.z = bf2f(ea.z) + bf2f(ca.z) + p.z;
                hv.w = bf2f(ea.w) + bf2f(ca.w) + p.w;
            }
            h[w5*4+0] = hv.x; h[w5*4+1] = hv.y; h[w5*4+2] = hv.z; h[w5*4+3] = hv.w;
            s += hv.x + hv.y + hv.z + hv.w;
            ss = fmaf(hv.x, hv.x, ss); ss = fmaf(hv.y, hv.y, ss);
            ss = fmaf(hv.z, hv.z, ss); ss = fmaf(hv.w, hv.w, ss);
        }
#pragma unroll
        for (int off = 1; off < 16; off <<= 1) {
            s  += __shfl_xor(s, off);
            ss += __shfl_xor(ss, off);
        }
        const float mu   = s * inv;
        const float rsig = rsqrtf(ss * inv - mu * mu + LN_EPS);

        float acc = 0.f;
#pragma unroll
        for (int w5 = 0; w5 < 5; ++w5) {
            int c = w5 * 64 + fl * 4;
            if (c < H_DIM) {
                float4 g = *(const float4*)(ln_g + c);
                float4 bb = *(const float4*)(ln_b + c);
                float4 w = *(const float4*)(W2 + c);
                float t0 = fmaf((h[w5*4+0] - mu) * rsig, g.x, bb.x);
                float t1 = fmaf((h[w5*4+1] - mu) * rsig, g.y, bb.y);
                float t2 = fmaf((h[w5*4+2] - mu) * rsig, g.z, bb.z);
                float t3 = fmaf((h[w5*4+3] - mu) * rsig, g.w, bb.w);
                t0 = t0 > 0.f ? t0 : __expf(t0) - 1.f;
                t1 = t1 > 0.f ? t1 : __expf(t1) - 1.f;
                t2 = t2 > 0.f ? t2 : __expf(t2) - 1.f;
                t3 = t3 > 0.f ? t3 : __expf(t3) - 1.f;
                acc = fmaf(t0, w.x, acc); acc = fmaf(t1, w.y, acc);
                acc = fmaf(t2, w.z, acc); acc = fmaf(t3, w.w, acc);
            }
        }
#pragma unroll
        for (int off = 1; off < 16; off <<= 1) acc += __shfl_xor(acc, off);

        if (fl == 0 && active) {
            const int jb = ii - KWIN < 0 ? 0 : ii - KWIN;
            const int n = rowstart(ii) + (j - jb);
            out[(size_t)b * NC + n] = acc + b2v;
            if (b == 0) {
                posout[2 * (size_t)n]     = (float)(ii + 1);
                posout[2 * (size_t)n + 1] = (float)(j + 1);
            }
        }
    }
}

// ---------------------------------------------------------------------------
extern "C" void kernel_launch(void* const* d_in, const int* in_sizes, int n_in,
                              void* d_out, int out_size, void* d_ws, size_t ws_size,
                              hipStream_t stream) {
    const float* h_e     = (const float*)d_in[0];
    const float* h_c     = (const float*)d_in[1];
    const float* h_share = (const float*)d_in[2];
    // d_in[3] = mask (unused)
    const float* pos_W   = (const float*)d_in[4];
    const float* W1      = (const float*)d_in[5];
    const float* b1      = (const float*)d_in[6];
    const float* ln_g    = (const float*)d_in[7];
    const float* ln_b    = (const float*)d_in[8];
    const float* W2      = (const float*)d_in[9];
    const float* b2      = (const float*)d_in[10];

    float* ws   = (float*)d_ws;
    float* prel = ws + PREL_OFF;
    short* Wb   = (short*)(ws + WB_OFF);

    float* out    = (float*)d_out;
    float* posout = out + BNC;

    prep_kernel<<<13 + (2 * WNPAD * WKSTR) / 256, 256, 0, stream>>>(
        pos_W, W1, b1, prel, Wb);

    fused_kernel<<<NB * (L_SEQ / ITILE), 512, 0, stream>>>(
        h_e, h_c, h_share, Wb, prel, ln_g, ln_b, W2, b2, out, posout);
}